// Round 10
// baseline (127.325 us; speedup 1.0000x reference)
//
#include <hip/hip_runtime.h>

#define BLOCK 256
#define LOG_2PI_F 1.8378770664093453f

// ws layout (float offsets):
//   0..7   : stats: [2] ld_sum0 [3] ld_sum1 [4] cnt0 [5] cnt1
//   16     : p_tab [2*D]   (= 0.5*exp(-2*lsd))
//   16+2D  : q_tab [2*D]   (= 2*p*mu)
//   PART0  : partials [2(z)][G][2][Dp]   (plane 0 = sumAll, 1 = sumC1), Dp = D
//
// out layout: [0] prior | [1,1+2D) mus | [1+2D,1+4D) lsds |
//             [1+4D,1+4D+N) logp | [1+4D+N, +2) log_p_total

__device__ __forceinline__ void acc4(float4& s, const float4 d) {
    s.x += d.x; s.y += d.y; s.z += d.z; s.w += d.w;
}
__device__ __forceinline__ void fma4(float4& s, const float4 d, const float w) {
    s.x = fmaf(d.x, w, s.x); s.y = fmaf(d.y, w, s.y);
    s.z = fmaf(d.z, w, s.z); s.w = fmaf(d.w, w, s.w);
}

// shared stats helper: counts + per-class logdet sums (run by one block)
__device__ void do_stats(const int* __restrict__ target,
                         const float* __restrict__ logdet,
                         float* __restrict__ stats, int N)
{
    const int tid = threadIdx.x;
    float ldA = 0.f, ld1 = 0.f;
    int   c1  = 0;
    if ((N & 3) == 0) {
        const int4*   t4 = reinterpret_cast<const int4*>(target);
        const float4* l4 = reinterpret_cast<const float4*>(logdet);
        for (int i = tid; i < (N >> 2); i += BLOCK) {
            const int4   t = t4[i];
            const float4 v = l4[i];
            ldA += v.x + v.y + v.z + v.w;
            if (t.x) { c1++; ld1 += v.x; }
            if (t.y) { c1++; ld1 += v.y; }
            if (t.z) { c1++; ld1 += v.z; }
            if (t.w) { c1++; ld1 += v.w; }
        }
    } else {
        for (int n = tid; n < N; n += BLOCK) {
            const float v = logdet[n];
            ldA += v;
            if (target[n]) { c1++; ld1 += v; }
        }
    }
    __shared__ float sB[BLOCK], sC[BLOCK];
    __shared__ int   sI[BLOCK];
    sB[tid] = ldA; sC[tid] = ld1; sI[tid] = c1;
    __syncthreads();
    for (int off = BLOCK / 2; off > 0; off >>= 1) {
        if (tid < off) {
            sB[tid] += sB[tid + off];
            sC[tid] += sC[tid + off];
            sI[tid] += sI[tid + off];
        }
        __syncthreads();
    }
    if (tid == 0) {
        stats[2] = sB[0] - sC[0];          // ld_sum0
        stats[3] = sC[0];                  // ld_sum1
        stats[4] = (float)(N - sI[0]);     // cnt0
        stats[5] = (float)sI[0];           // cnt1
    }
}

// fast path (D == 3072): k_logp-shaped streaming.
// Block b = row slot; its 4 waves each own a CONTIGUOUS quarter-row
// (3 float4/lane). Wave folds rows {b, b+G, b+2G, ...} — small VGPR
// footprint (24 acc) -> 8 waves/SIMD; 2*G blocks -> 8 blocks/CU.
__global__ __launch_bounds__(BLOCK, 8) void k_colsum3(
    const float* __restrict__ mean,
    const float* __restrict__ log_sd,
    const int*   __restrict__ target,
    const float* __restrict__ logdet,
    float* __restrict__ partials,
    float* __restrict__ stats,
    int N, int G)
{
    const int tid  = threadIdx.x;
    const int wave = tid >> 6;
    const int lane = tid & 63;
    const int b    = blockIdx.x;            // row slot, 0..G-1
    const int z    = blockIdx.y;
    const int D4   = 768;                   // 3072/4

    const float4* src4 =
        reinterpret_cast<const float4*>(z == 0 ? mean : log_sd);
    // wave's quarter: col-quads [wave*192, wave*192+192); lane gets 3 quads
    const float4* p = src4 + (size_t)b * D4 + wave * 192 + lane;
    const size_t rstep = (size_t)G * D4;    // row stride in float4s

    float4 A0 = make_float4(0.f,0.f,0.f,0.f);
    float4 A1 = make_float4(0.f,0.f,0.f,0.f);
    float4 A2 = make_float4(0.f,0.f,0.f,0.f);
    float4 C0 = make_float4(0.f,0.f,0.f,0.f);
    float4 C1 = make_float4(0.f,0.f,0.f,0.f);
    float4 C2 = make_float4(0.f,0.f,0.f,0.f);

    int row = b;
    const float4* pr = p;
    // unroll 2 rows: 6 independent sequential-chunk loads visible
    for (; row + G < N; row += 2 * G, pr += 2 * rstep) {
        const float wa = target[row]     ? 1.f : 0.f;
        const float wb = target[row + G] ? 1.f : 0.f;
        const float4 a0 = pr[0];
        const float4 a1 = pr[64];
        const float4 a2 = pr[128];
        const float4 b0 = pr[rstep];
        const float4 b1 = pr[rstep + 64];
        const float4 b2 = pr[rstep + 128];
        acc4(A0, a0); fma4(C0, a0, wa);
        acc4(A1, a1); fma4(C1, a1, wa);
        acc4(A2, a2); fma4(C2, a2, wa);
        acc4(A0, b0); fma4(C0, b0, wb);
        acc4(A1, b1); fma4(C1, b1, wb);
        acc4(A2, b2); fma4(C2, b2, wb);
    }
    if (row < N) {                          // tail row
        const float w = target[row] ? 1.f : 0.f;
        const float4 a0 = pr[0];
        const float4 a1 = pr[64];
        const float4 a2 = pr[128];
        acc4(A0, a0); fma4(C0, a0, w);
        acc4(A1, a1); fma4(C1, a1, w);
        acc4(A2, a2); fma4(C2, a2, w);
    }

    // coalesced partial stores: [plane0|plane1] x 3072 floats per slot
    float* base = partials + ((size_t)z * G + b) * (2 * 3072);
    float4* pl0 = reinterpret_cast<float4*>(base);
    float4* pl1 = reinterpret_cast<float4*>(base + 3072);
    const int o = wave * 192 + lane;
    pl0[o] = A0; pl0[o + 64] = A1; pl0[o + 128] = A2;
    pl1[o] = C0; pl1[o + 64] = C1; pl1[o + 128] = C2;

    if (b == 0 && z == 0) do_stats(target, logdet, stats, N);
}

// generic fallback (any D): round-robin rows, column-group blocks
__global__ __launch_bounds__(BLOCK, 4) void k_colsum_gen(
    const float* __restrict__ mean,
    const float* __restrict__ log_sd,
    const int*   __restrict__ target,
    const float* __restrict__ logdet,
    float* __restrict__ partials,
    float* __restrict__ stats,
    int N, int D4, int Dp, int G)
{
    const int c4 = blockIdx.x * BLOCK + threadIdx.x;
    const bool colOK = (c4 < D4);
    const int by = blockIdx.y;

    const float4* src4 =
        reinterpret_cast<const float4*>(blockIdx.z == 0 ? mean : log_sd);
    const float4* p = src4 + (size_t)by * D4 + (colOK ? c4 : 0);
    const size_t rstep = (size_t)G * D4;
    const int nk = (by < N) ? ((N - 1 - by) / G + 1) : 0;

    float4 sA = make_float4(0.f,0.f,0.f,0.f);
    float4 s1 = make_float4(0.f,0.f,0.f,0.f);
    for (int k = 0; k < nk; ++k) {
        const float w = target[by + k * G] ? 1.f : 0.f;
        const float4 d = p[(size_t)k * rstep];
        acc4(sA, d); fma4(s1, d, w);
    }

    if (colOK) {
        float* base = partials +
            ((size_t)blockIdx.z * G + by) * (2 * (size_t)Dp);
        reinterpret_cast<float4*>(base)[c4]      = sA;
        reinterpret_cast<float4*>(base + Dp)[c4] = s1;
    }
    if (blockIdx.x == 0 && by == 0 && blockIdx.z == 0)
        do_stats(target, logdet, stats, N);
}

// reduce partials over G slots (8 threads per output), finalize params+tables
__global__ __launch_bounds__(BLOCK) void k_reduce_finalize(
    const float* __restrict__ partials,
    float* __restrict__ ws,
    float* __restrict__ out,
    int D, int Dp, int G)
{
    const int sub  = threadIdx.x & 7;
    const int slot = threadIdx.x >> 3;                 // 0..31
    const int oidx = blockIdx.x * 32 + slot;           // [0, 2*D)
    const bool ok  = (oidx < 2 * D);
    const int cls = ok ? (oidx / D) : 0;
    const int col = ok ? (oidx - cls * D) : 0;

    const size_t strideBY = 2 * (size_t)Dp;
    const size_t zoff     = (size_t)G * strideBY;
    const int per = G >> 3;

    float mA = 0.f, m1 = 0.f, lA = 0.f, l1 = 0.f;
    for (int j = 0; j < per; ++j) {
        const size_t base = (size_t)(sub * per + j) * strideBY + col;
        mA += partials[base];
        m1 += partials[base + Dp];
        lA += partials[zoff + base];
        l1 += partials[zoff + base + Dp];
    }
    #pragma unroll
    for (int s = 1; s <= 4; s <<= 1) {
        mA += __shfl_xor(mA, s);
        m1 += __shfl_xor(m1, s);
        lA += __shfl_xor(lA, s);
        l1 += __shfl_xor(l1, s);
    }

    if (ok && sub == 0) {
        const float cnt = ws[4 + cls];
        const float m = (cls ? m1 : (mA - m1)) / cnt;
        const float l = (cls ? l1 : (lA - l1)) / cnt;
        out[1 + oidx]         = m;   // mus
        out[1 + 2 * D + oidx] = l;   // lsds
        float* p_tab = ws + 16;
        float* q_tab = p_tab + 2 * D;
        const float pv = 0.5f * expf(-2.f * l);
        p_tab[oidx] = pv;
        q_tab[oidx] = 2.f * pv * m;
    }
}

__global__ __launch_bounds__(BLOCK) void k_logp(
    const float* __restrict__ z,
    const int*   __restrict__ target,
    const float* __restrict__ ws,
    float* __restrict__ logp_out,
    int N, int D)
{
    const int wave = threadIdx.x >> 6;
    const int lane = threadIdx.x & 63;
    const int n    = blockIdx.x * 4 + wave;
    const int D4   = D >> 2;
    if (n >= N) return;

    const int t = __builtin_amdgcn_readfirstlane(target[n]);
    const float4* z4 = reinterpret_cast<const float4*>(z) + (size_t)n * D4;
    const float4* p4 = reinterpret_cast<const float4*>(ws + 16) + (size_t)t * D4;
    const float4* q4 = p4 + 2 * D4;

    float acc = 0.f;
    int i = lane;
    for (; i + 64 < D4; i += 128) {
        const float4 zz0 = z4[i];      const float4 zz1 = z4[i + 64];
        const float4 pp0 = p4[i];      const float4 pp1 = p4[i + 64];
        const float4 qq0 = q4[i];      const float4 qq1 = q4[i + 64];
        acc += zz0.x * (qq0.x - pp0.x * zz0.x);
        acc += zz0.y * (qq0.y - pp0.y * zz0.y);
        acc += zz0.z * (qq0.z - pp0.z * zz0.z);
        acc += zz0.w * (qq0.w - pp0.w * zz0.w);
        acc += zz1.x * (qq1.x - pp1.x * zz1.x);
        acc += zz1.y * (qq1.y - pp1.y * zz1.y);
        acc += zz1.z * (qq1.z - pp1.z * zz1.z);
        acc += zz1.w * (qq1.w - pp1.w * zz1.w);
    }
    for (; i < D4; i += 64) {
        const float4 zz = z4[i];
        const float4 pp = p4[i];
        const float4 qq = q4[i];
        acc += zz.x * (qq.x - pp.x * zz.x);
        acc += zz.y * (qq.y - pp.y * zz.y);
        acc += zz.z * (qq.z - pp.z * zz.z);
        acc += zz.w * (qq.w - pp.w * zz.w);
    }

    #pragma unroll
    for (int m = 32; m >= 1; m >>= 1) acc += __shfl_xor(acc, m);
    if (lane == 0) logp_out[n] = acc;        // Bc added in k_finalize2
}

// epilogue: per-class Bc from mus/lsds, patch logp, class means, prior
__global__ __launch_bounds__(1024) void k_finalize2(
    const int*   __restrict__ target,
    const float* __restrict__ stats,
    float* __restrict__ out,
    int N, int D, int out_off)
{
    const int tid = threadIdx.x;
    const float* mus  = out + 1;
    const float* lsds = out + 1 + 2 * D;
    float* logp = out + 1 + 4 * D;

    // phase 1: Bc[cls] = sum_d ( -0.5*log2pi - l - 0.5*exp(-2l)*m^2 )
    float b0 = 0.f, b1 = 0.f;
    for (int idx = tid; idx < 2 * D; idx += 1024) {
        const float m = mus[idx];
        const float l = lsds[idx];
        const float b = -0.5f * LOG_2PI_F - l - 0.5f * expf(-2.f * l) * m * m;
        if (idx < D) b0 += b; else b1 += b;
    }
    __shared__ float s0[1024];
    __shared__ float s1[1024];
    s0[tid] = b0; s1[tid] = b1;
    __syncthreads();
    for (int off = 512; off > 0; off >>= 1) {
        if (tid < off) {
            s0[tid] += s0[tid + off];
            s1[tid] += s1[tid + off];
        }
        __syncthreads();
    }
    const float B0 = s0[0];
    const float B1 = s1[0];
    __syncthreads();

    // phase 2: patch logp with Bc, accumulate per-class sums
    float cA = 0.f, c1 = 0.f;
    for (int i = tid; i < N; i += 1024) {
        const int   t = target[i];
        const float v = logp[i] + (t ? B1 : B0);
        logp[i] = v;
        cA += v;
        if (t) c1 += v;
    }
    s0[tid] = cA; s1[tid] = c1;
    __syncthreads();
    for (int off = 512; off > 0; off >>= 1) {
        if (tid < off) {
            s0[tid] += s0[tid + off];
            s1[tid] += s1[tid + off];
        }
        __syncthreads();
    }
    if (tid == 0) {
        const float lp0 = (s0[0] - s1[0]) / stats[4];
        const float lp1 = s1[0] / stats[5];
        const float ld0 = stats[2] / stats[4];
        const float ld1 = stats[3] / stats[5];
        out[out_off]     = lp0;            // log_p_total[0]
        out[out_off + 1] = lp1;            // log_p_total[1]
        out[0] = 0.5f * ((lp0 + ld0) + (lp1 + ld1));  // prior_logprob
    }
}

extern "C" void kernel_launch(void* const* d_in, const int* in_sizes, int n_in,
                              void* d_out, int out_size, void* d_ws, size_t ws_size,
                              hipStream_t stream)
{
    const float* z      = (const float*)d_in[0];
    const float* mean   = (const float*)d_in[1];
    const float* log_sd = (const float*)d_in[2];
    const float* logdet = (const float*)d_in[3];
    const int*   target = (const int*)d_in[4];
    float* out = (float*)d_out;
    float* ws  = (float*)d_ws;

    const int N  = in_sizes[3];            // 8192
    const int D  = in_sizes[0] / N;        // 3072
    const int D4 = D >> 2;                 // 768
    const int Dp = D4 * 4;                 // plane width (== D here)

    size_t part0 = (size_t)(16 + 4 * D);
    part0 = (part0 + 255) & ~(size_t)255;

    // pick G (power of 2, >= 8): 1024 -> 2048 blocks (8/CU), 48 MB partials;
    // shrink if ws can't hold them
    int G = 1024;
    while (G > 8 &&
           (part0 + (size_t)2 * G * 2 * Dp) * sizeof(float) > ws_size)
        G >>= 1;

    float* partials = ws + part0;

    // pass 1: k_logp-shaped streaming per-class column partial sums
    if (D4 == 768) {
        dim3 g1(G, 2);
        k_colsum3<<<g1, BLOCK, 0, stream>>>(mean, log_sd, target, logdet,
                                            partials, ws, N, G);
    } else {
        dim3 g1((D4 + BLOCK - 1) / BLOCK, G, 2);
        k_colsum_gen<<<g1, BLOCK, 0, stream>>>(mean, log_sd, target, logdet,
                                               partials, ws, N, D4, Dp, G);
    }

    // reduce partials + finalize class params + build p/q tables
    const int nred = (2 * D + 31) / 32;
    k_reduce_finalize<<<nred, BLOCK, 0, stream>>>(partials, ws, out, D, Dp, G);

    // pass 2: per-sample logp (one wave per row)
    float* logp_out = out + 1 + 4 * D;
    k_logp<<<(N + 3) / 4, BLOCK, 0, stream>>>(z, target, ws, logp_out, N, D);

    // epilogue: Bc + patch logp + class means + prior
    k_finalize2<<<1, 1024, 0, stream>>>(target, ws, out, N, D, 1 + 4 * D + N);
}

// Round 11
// 99.038 us; speedup vs baseline: 1.2856x; 1.2856x over previous
//
#include <hip/hip_runtime.h>

#define BLOCK 256
#define LOG_2PI_F 1.8378770664093453f

// ws layout (float offsets):
//   0..7   : stats: [2] ld_sum0 [3] ld_sum1 [4] cnt0 [5] cnt1
//   16     : p_tab [2*D]   (= 0.5*exp(-2*lsd))
//   16+2D  : q_tab [2*D]   (= 2*p*mu)
//   PART0  : partials [2(z)][G][2][Dp]   (plane 0 = sumAll, 1 = sumC1), Dp = D
//
// out layout: [0] prior | [1,1+2D) mus | [1+2D,1+4D) lsds |
//             [1+4D,1+4D+N) logp | [1+4D+N, +2) log_p_total

__device__ __forceinline__ void acc4(float4& s, const float4 d) {
    s.x += d.x; s.y += d.y; s.z += d.z; s.w += d.w;
}
__device__ __forceinline__ void fma4(float4& s, const float4 d, const float w) {
    s.x = fmaf(d.x, w, s.x); s.y = fmaf(d.y, w, s.y);
    s.z = fmaf(d.z, w, s.z); s.w = fmaf(d.w, w, s.w);
}

// async global->LDS 16B per lane: NO result VGPRs, stays in flight until vmcnt
__device__ __forceinline__ void gld_lds16(const float4* gp, float4* lp) {
    __builtin_amdgcn_global_load_lds(
        (const __attribute__((address_space(1))) void*)gp,
        (__attribute__((address_space(3))) void*)lp,
        16, 0, 0);
}

// shared stats helper: counts + per-class logdet sums (run by one block)
__device__ void do_stats(const int* __restrict__ target,
                         const float* __restrict__ logdet,
                         float* __restrict__ stats, int N)
{
    const int tid = threadIdx.x;
    float ldA = 0.f, ld1 = 0.f;
    int   c1  = 0;
    if ((N & 3) == 0) {
        const int4*   t4 = reinterpret_cast<const int4*>(target);
        const float4* l4 = reinterpret_cast<const float4*>(logdet);
        for (int i = tid; i < (N >> 2); i += BLOCK) {
            const int4   t = t4[i];
            const float4 v = l4[i];
            ldA += v.x + v.y + v.z + v.w;
            if (t.x) { c1++; ld1 += v.x; }
            if (t.y) { c1++; ld1 += v.y; }
            if (t.z) { c1++; ld1 += v.z; }
            if (t.w) { c1++; ld1 += v.w; }
        }
    } else {
        for (int n = tid; n < N; n += BLOCK) {
            const float v = logdet[n];
            ldA += v;
            if (target[n]) { c1++; ld1 += v; }
        }
    }
    __shared__ float sB[BLOCK], sC[BLOCK];
    __shared__ int   sI[BLOCK];
    sB[tid] = ldA; sC[tid] = ld1; sI[tid] = c1;
    __syncthreads();
    for (int off = BLOCK / 2; off > 0; off >>= 1) {
        if (tid < off) {
            sB[tid] += sB[tid + off];
            sC[tid] += sC[tid + off];
            sI[tid] += sI[tid + off];
        }
        __syncthreads();
    }
    if (tid == 0) {
        stats[2] = sB[0] - sC[0];          // ld_sum0
        stats[3] = sC[0];                  // ld_sum1
        stats[4] = (float)(N - sI[0]);     // cnt0
        stats[5] = (float)sI[0];           // cnt1
    }
}

// fast path (D == 3072): wave-private 3-deep global_load_lds pipeline.
// Block b, wave w: columns quads [w*192,(w+1)*192), rows {b, b+G, ...}.
// Staging needs zero VGPRs -> guaranteed multi-row in flight; counted
// vmcnt(6) steady-state wait; no block barriers in the pipeline.
__global__ __launch_bounds__(BLOCK) void k_colsum3(
    const float* __restrict__ mean,
    const float* __restrict__ log_sd,
    const int*   __restrict__ target,
    const float* __restrict__ logdet,
    float* __restrict__ partials,
    float* __restrict__ stats,
    int N, int G)
{
    const int tid  = threadIdx.x;
    const int wave = tid >> 6;
    const int lane = tid & 63;
    const int b    = blockIdx.x;            // row slot, 0..G-1
    const int z    = blockIdx.y;
    const int D4   = 768;                   // 3072/4

    __shared__ float4 lds[3][4][192];       // 3 slots x 4 waves x 3KB = 36KB
    __shared__ float  wrow[128];            // per-block row weights

    const float4* src4 =
        reinterpret_cast<const float4*>(z == 0 ? mean : log_sd);
    const int nk = (b < N) ? ((N - 1 - b) / G + 1) : 0;   // rows this block

    // prefetch weights (removes all vmcnt ops from the consume loop)
    for (int i = tid; i < nk && i < 128; i += BLOCK)
        wrow[i] = target[b + i * G] ? 1.f : 0.f;
    __syncthreads();

    float4 A0 = make_float4(0.f,0.f,0.f,0.f);
    float4 A1 = make_float4(0.f,0.f,0.f,0.f);
    float4 A2 = make_float4(0.f,0.f,0.f,0.f);
    float4 C0 = make_float4(0.f,0.f,0.f,0.f);
    float4 C1 = make_float4(0.f,0.f,0.f,0.f);
    float4 C2 = make_float4(0.f,0.f,0.f,0.f);

    auto stage = [&](int k, int slot) {
        const float4* rp = src4 + (size_t)(b + (size_t)k * G) * D4
                                + wave * 192 + lane;
        gld_lds16(rp,       &lds[slot][wave][0]);
        gld_lds16(rp + 64,  &lds[slot][wave][64]);
        gld_lds16(rp + 128, &lds[slot][wave][128]);
    };

    if (nk > 0) stage(0, 0);
    if (nk > 1) stage(1, 1);

    for (int k = 0; k < nk; ++k) {
        if (k + 2 < nk) stage(k + 2, (k + 2) % 3);
        const int ahead = nk - 1 - k;
        if (ahead >= 2)      asm volatile("s_waitcnt vmcnt(6)" ::: "memory");
        else if (ahead == 1) asm volatile("s_waitcnt vmcnt(3)" ::: "memory");
        else                 asm volatile("s_waitcnt vmcnt(0)" ::: "memory");
        __builtin_amdgcn_sched_barrier(0);   // rule #18: consumers stay below
        const int s = k % 3;
        const float w = wrow[k];
        const float4 d0 = lds[s][wave][lane];
        const float4 d1 = lds[s][wave][64 + lane];
        const float4 d2 = lds[s][wave][128 + lane];
        acc4(A0, d0); fma4(C0, d0, w);
        acc4(A1, d1); fma4(C1, d1, w);
        acc4(A2, d2); fma4(C2, d2, w);
    }

    // coalesced partial stores: [plane0|plane1] x 3072 floats per slot
    float* base = partials + ((size_t)z * G + b) * (2 * 3072);
    float4* pl0 = reinterpret_cast<float4*>(base);
    float4* pl1 = reinterpret_cast<float4*>(base + 3072);
    const int o = wave * 192 + lane;
    pl0[o] = A0; pl0[o + 64] = A1; pl0[o + 128] = A2;
    pl1[o] = C0; pl1[o + 64] = C1; pl1[o + 128] = C2;

    if (b == 0 && z == 0) do_stats(target, logdet, stats, N);
}

// generic fallback (any D): round-robin rows, column-group blocks
__global__ __launch_bounds__(BLOCK, 4) void k_colsum_gen(
    const float* __restrict__ mean,
    const float* __restrict__ log_sd,
    const int*   __restrict__ target,
    const float* __restrict__ logdet,
    float* __restrict__ partials,
    float* __restrict__ stats,
    int N, int D4, int Dp, int G)
{
    const int c4 = blockIdx.x * BLOCK + threadIdx.x;
    const bool colOK = (c4 < D4);
    const int by = blockIdx.y;

    const float4* src4 =
        reinterpret_cast<const float4*>(blockIdx.z == 0 ? mean : log_sd);
    const float4* p = src4 + (size_t)by * D4 + (colOK ? c4 : 0);
    const size_t rstep = (size_t)G * D4;
    const int nk = (by < N) ? ((N - 1 - by) / G + 1) : 0;

    float4 sA = make_float4(0.f,0.f,0.f,0.f);
    float4 s1 = make_float4(0.f,0.f,0.f,0.f);
    for (int k = 0; k < nk; ++k) {
        const float w = target[by + k * G] ? 1.f : 0.f;
        const float4 d = p[(size_t)k * rstep];
        acc4(sA, d); fma4(s1, d, w);
    }

    if (colOK) {
        float* base = partials +
            ((size_t)blockIdx.z * G + by) * (2 * (size_t)Dp);
        reinterpret_cast<float4*>(base)[c4]      = sA;
        reinterpret_cast<float4*>(base + Dp)[c4] = s1;
    }
    if (blockIdx.x == 0 && by == 0 && blockIdx.z == 0)
        do_stats(target, logdet, stats, N);
}

// reduce partials over G slots (8 threads per output), finalize params+tables
__global__ __launch_bounds__(BLOCK) void k_reduce_finalize(
    const float* __restrict__ partials,
    float* __restrict__ ws,
    float* __restrict__ out,
    int D, int Dp, int G)
{
    const int sub  = threadIdx.x & 7;
    const int slot = threadIdx.x >> 3;                 // 0..31
    const int oidx = blockIdx.x * 32 + slot;           // [0, 2*D)
    const bool ok  = (oidx < 2 * D);
    const int cls = ok ? (oidx / D) : 0;
    const int col = ok ? (oidx - cls * D) : 0;

    const size_t strideBY = 2 * (size_t)Dp;
    const size_t zoff     = (size_t)G * strideBY;
    const int per = G >> 3;

    float mA = 0.f, m1 = 0.f, lA = 0.f, l1 = 0.f;
    for (int j = 0; j < per; ++j) {
        const size_t base = (size_t)(sub * per + j) * strideBY + col;
        mA += partials[base];
        m1 += partials[base + Dp];
        lA += partials[zoff + base];
        l1 += partials[zoff + base + Dp];
    }
    #pragma unroll
    for (int s = 1; s <= 4; s <<= 1) {
        mA += __shfl_xor(mA, s);
        m1 += __shfl_xor(m1, s);
        lA += __shfl_xor(lA, s);
        l1 += __shfl_xor(l1, s);
    }

    if (ok && sub == 0) {
        const float cnt = ws[4 + cls];
        const float m = (cls ? m1 : (mA - m1)) / cnt;
        const float l = (cls ? l1 : (lA - l1)) / cnt;
        out[1 + oidx]         = m;   // mus
        out[1 + 2 * D + oidx] = l;   // lsds
        float* p_tab = ws + 16;
        float* q_tab = p_tab + 2 * D;
        const float pv = 0.5f * expf(-2.f * l);
        p_tab[oidx] = pv;
        q_tab[oidx] = 2.f * pv * m;
    }
}

__global__ __launch_bounds__(BLOCK) void k_logp(
    const float* __restrict__ z,
    const int*   __restrict__ target,
    const float* __restrict__ ws,
    float* __restrict__ logp_out,
    int N, int D)
{
    const int wave = threadIdx.x >> 6;
    const int lane = threadIdx.x & 63;
    const int n    = blockIdx.x * 4 + wave;
    const int D4   = D >> 2;
    if (n >= N) return;

    const int t = __builtin_amdgcn_readfirstlane(target[n]);
    const float4* z4 = reinterpret_cast<const float4*>(z) + (size_t)n * D4;
    const float4* p4 = reinterpret_cast<const float4*>(ws + 16) + (size_t)t * D4;
    const float4* q4 = p4 + 2 * D4;

    float acc = 0.f;
    int i = lane;
    for (; i + 64 < D4; i += 128) {
        const float4 zz0 = z4[i];      const float4 zz1 = z4[i + 64];
        const float4 pp0 = p4[i];      const float4 pp1 = p4[i + 64];
        const float4 qq0 = q4[i];      const float4 qq1 = q4[i + 64];
        acc += zz0.x * (qq0.x - pp0.x * zz0.x);
        acc += zz0.y * (qq0.y - pp0.y * zz0.y);
        acc += zz0.z * (qq0.z - pp0.z * zz0.z);
        acc += zz0.w * (qq0.w - pp0.w * zz0.w);
        acc += zz1.x * (qq1.x - pp1.x * zz1.x);
        acc += zz1.y * (qq1.y - pp1.y * zz1.y);
        acc += zz1.z * (qq1.z - pp1.z * zz1.z);
        acc += zz1.w * (qq1.w - pp1.w * zz1.w);
    }
    for (; i < D4; i += 64) {
        const float4 zz = z4[i];
        const float4 pp = p4[i];
        const float4 qq = q4[i];
        acc += zz.x * (qq.x - pp.x * zz.x);
        acc += zz.y * (qq.y - pp.y * zz.y);
        acc += zz.z * (qq.z - pp.z * zz.z);
        acc += zz.w * (qq.w - pp.w * zz.w);
    }

    #pragma unroll
    for (int m = 32; m >= 1; m >>= 1) acc += __shfl_xor(acc, m);
    if (lane == 0) logp_out[n] = acc;        // Bc added in k_finalize2
}

// epilogue: per-class Bc from mus/lsds, patch logp, class means, prior
__global__ __launch_bounds__(1024) void k_finalize2(
    const int*   __restrict__ target,
    const float* __restrict__ stats,
    float* __restrict__ out,
    int N, int D, int out_off)
{
    const int tid = threadIdx.x;
    const float* mus  = out + 1;
    const float* lsds = out + 1 + 2 * D;
    float* logp = out + 1 + 4 * D;

    // phase 1: Bc[cls] = sum_d ( -0.5*log2pi - l - 0.5*exp(-2l)*m^2 )
    float b0 = 0.f, b1 = 0.f;
    for (int idx = tid; idx < 2 * D; idx += 1024) {
        const float m = mus[idx];
        const float l = lsds[idx];
        const float b = -0.5f * LOG_2PI_F - l - 0.5f * expf(-2.f * l) * m * m;
        if (idx < D) b0 += b; else b1 += b;
    }
    __shared__ float s0[1024];
    __shared__ float s1[1024];
    s0[tid] = b0; s1[tid] = b1;
    __syncthreads();
    for (int off = 512; off > 0; off >>= 1) {
        if (tid < off) {
            s0[tid] += s0[tid + off];
            s1[tid] += s1[tid + off];
        }
        __syncthreads();
    }
    const float B0 = s0[0];
    const float B1 = s1[0];
    __syncthreads();

    // phase 2: patch logp with Bc, accumulate per-class sums
    float cA = 0.f, c1 = 0.f;
    for (int i = tid; i < N; i += 1024) {
        const int   t = target[i];
        const float v = logp[i] + (t ? B1 : B0);
        logp[i] = v;
        cA += v;
        if (t) c1 += v;
    }
    s0[tid] = cA; s1[tid] = c1;
    __syncthreads();
    for (int off = 512; off > 0; off >>= 1) {
        if (tid < off) {
            s0[tid] += s0[tid + off];
            s1[tid] += s1[tid + off];
        }
        __syncthreads();
    }
    if (tid == 0) {
        const float lp0 = (s0[0] - s1[0]) / stats[4];
        const float lp1 = s1[0] / stats[5];
        const float ld0 = stats[2] / stats[4];
        const float ld1 = stats[3] / stats[5];
        out[out_off]     = lp0;            // log_p_total[0]
        out[out_off + 1] = lp1;            // log_p_total[1]
        out[0] = 0.5f * ((lp0 + ld0) + (lp1 + ld1));  // prior_logprob
    }
}

extern "C" void kernel_launch(void* const* d_in, const int* in_sizes, int n_in,
                              void* d_out, int out_size, void* d_ws, size_t ws_size,
                              hipStream_t stream)
{
    const float* z      = (const float*)d_in[0];
    const float* mean   = (const float*)d_in[1];
    const float* log_sd = (const float*)d_in[2];
    const float* logdet = (const float*)d_in[3];
    const int*   target = (const int*)d_in[4];
    float* out = (float*)d_out;
    float* ws  = (float*)d_ws;

    const int N  = in_sizes[3];            // 8192
    const int D  = in_sizes[0] / N;        // 3072
    const int D4 = D >> 2;                 // 768
    const int Dp = D4 * 4;                 // plane width (== D here)

    size_t part0 = (size_t)(16 + 4 * D);
    part0 = (part0 + 255) & ~(size_t)255;

    // pick G (power of 2, >= 8): 512 -> 1024 blocks (4/CU by LDS), 25MB partials
    int G = 512;
    while (G > 8 &&
           (part0 + (size_t)2 * G * 2 * Dp) * sizeof(float) > ws_size)
        G >>= 1;

    float* partials = ws + part0;

    const int nkMax = (N + G - 1) / G;

    // pass 1: async-pipelined per-class column partial sums
    if (D4 == 768 && nkMax <= 128) {
        dim3 g1(G, 2);
        k_colsum3<<<g1, BLOCK, 0, stream>>>(mean, log_sd, target, logdet,
                                            partials, ws, N, G);
    } else {
        dim3 g1((D4 + BLOCK - 1) / BLOCK, G, 2);
        k_colsum_gen<<<g1, BLOCK, 0, stream>>>(mean, log_sd, target, logdet,
                                               partials, ws, N, D4, Dp, G);
    }

    // reduce partials + finalize class params + build p/q tables
    const int nred = (2 * D + 31) / 32;
    k_reduce_finalize<<<nred, BLOCK, 0, stream>>>(partials, ws, out, D, Dp, G);

    // pass 2: per-sample logp (one wave per row)
    float* logp_out = out + 1 + 4 * D;
    k_logp<<<(N + 3) / 4, BLOCK, 0, stream>>>(z, target, ws, logp_out, N, D);

    // epilogue: Bc + patch logp + class means + prior
    k_finalize2<<<1, 1024, 0, stream>>>(target, ws, out, N, D, 1 + 4 * D + N);
}